// Round 1
// baseline (327.889 us; speedup 1.0000x reference)
//
#include <hip/hip_runtime.h>
#include <hip/hip_bf16.h>

// PeakBinner: out[b, g*50+o] = relu( sum_k x[b, g*250+k] * W[g,o,k] )
// b in [0,4096), g in [0,39), o in [0,50), k in [0,500)
// Strategy: 39 independent GEMMs (M=4096, N=50->pad 64, K=500->pad 512),
// bf16 MFMA 16x16x32 with fp32->bf16 conversion fused into LDS staging.

constexpr int INPUT  = 10000;
constexpr int GROUPS = 39;
constexpr int GS     = 500;
constexpr int STEP   = 250;
constexpr int OPG    = 50;
constexpr int OUTW   = GROUPS * OPG;   // 1950

constexpr int BM = 128;
constexpr int BN = 64;                 // covers 50 outputs (padded)
constexpr int BK = 64;
constexpr int NSTAGE = 8;              // 8*64 = 512 >= 500 (zero-padded tail)
constexpr int LDA = BK + 8;            // +8 bf16 pad: frag reads 2-way (free) not 16-way
constexpr int LDB = BK + 8;

typedef __attribute__((ext_vector_type(8))) short  short8;   // 8 bf16 = 4 VGPRs
typedef __attribute__((ext_vector_type(4))) float  float4v;  // 4 fp32 acc

__device__ __forceinline__ short f2bf(float f) {
    // round-to-nearest-even fp32 -> bf16 (inputs are finite, no NaN path needed)
    union { float f; unsigned u; } a; a.f = f;
    unsigned r = (a.u + 0x7fffu + ((a.u >> 16) & 1u)) >> 16;
    return (short)r;
}

__global__ __launch_bounds__(256, 2)
void peak_binner_kernel(const float* __restrict__ x,
                        const float* __restrict__ W,
                        float* __restrict__ out, int batch)
{
    __shared__ __align__(16) short As[BM * LDA];
    __shared__ __align__(16) short Bs[BN * LDB];

    const int g    = blockIdx.x;        // group 0..38
    const int m0   = blockIdx.y * BM;   // batch-row tile base
    const int tid  = threadIdx.x;
    const int lane = tid & 63;
    const int wave = tid >> 6;          // 0..3, each wave: rows [wave*32, wave*32+32)

    float4v acc[2][4];
    #pragma unroll
    for (int i = 0; i < 2; ++i)
        #pragma unroll
        for (int j = 0; j < 4; ++j)
            acc[i][j] = {0.f, 0.f, 0.f, 0.f};

    const long  col0 = (long)g * STEP;
    const float* Wg  = W + (size_t)g * OPG * GS;

    // staging: lane -> (row, 4-float k chunk)
    const int tk = (tid & 15) * 4;      // k offset within tile
    const int tr = tid >> 4;            // row base 0..15

    // fragment addressing (A and B^T read identically for 16x16x32 bf16)
    const int fm = lane & 15;           // fragment row (m or o)
    const int fk = (lane >> 4) * 8;     // fragment k base

    for (int stage = 0; stage < NSTAGE; ++stage) {
        const int kb = stage * BK;
        __syncthreads();

        // ---- stage A tile (x): BM x BK, fp32 -> bf16 ----
        #pragma unroll
        for (int rr = 0; rr < BM / 16; ++rr) {
            const int r   = tr + rr * 16;
            const int row = m0 + r;
            const int kl  = kb + tk;
            float v0 = 0.f, v1 = 0.f, v2 = 0.f, v3 = 0.f;
            if (kl < GS && row < batch) {
                // x col base g*250 is only 8B-aligned for odd g -> float2 pairs
                const float* p = x + (long)row * INPUT + col0 + kl;
                float2 u0 = *(const float2*)(p);
                float2 u1 = *(const float2*)(p + 2);
                v0 = u0.x; v1 = u0.y; v2 = u1.x; v3 = u1.y;
            }
            short4 h;
            h.x = f2bf(v0); h.y = f2bf(v1); h.z = f2bf(v2); h.w = f2bf(v3);
            *(short4*)&As[r * LDA + tk] = h;
        }

        // ---- stage B tile (W[g]): BN x BK, fp32 -> bf16, zero-pad o>=50 ----
        #pragma unroll
        for (int rr = 0; rr < BN / 16; ++rr) {
            const int o  = tr + rr * 16;
            const int kl = kb + tk;
            float v0 = 0.f, v1 = 0.f, v2 = 0.f, v3 = 0.f;
            if (o < OPG && kl < GS) {
                const float4 u = *(const float4*)(Wg + o * GS + kl);
                v0 = u.x; v1 = u.y; v2 = u.z; v3 = u.w;
            }
            short4 h;
            h.x = f2bf(v0); h.y = f2bf(v1); h.z = f2bf(v2); h.w = f2bf(v3);
            *(short4*)&Bs[o * LDB + tk] = h;
        }
        __syncthreads();

        // ---- compute: 2 MFMA K-steps of 32 ----
        #pragma unroll
        for (int kk = 0; kk < BK; kk += 32) {
            short8 a[2], b[4];
            #pragma unroll
            for (int mt = 0; mt < 2; ++mt)
                a[mt] = *(const short8*)&As[(wave * 32 + mt * 16 + fm) * LDA + kk + fk];
            #pragma unroll
            for (int nt = 0; nt < 4; ++nt)
                b[nt] = *(const short8*)&Bs[(nt * 16 + fm) * LDB + kk + fk];
            #pragma unroll
            for (int mt = 0; mt < 2; ++mt)
                #pragma unroll
                for (int nt = 0; nt < 4; ++nt)
                    acc[mt][nt] = __builtin_amdgcn_mfma_f32_16x16x32_bf16(
                        a[mt], b[nt], acc[mt][nt], 0, 0, 0);
        }
    }

    // ---- epilogue: C/D layout col=lane&15, row=(lane>>4)*4+reg; relu + store ----
    const int orow = (lane >> 4) * 4;
    const int ocol = lane & 15;
    #pragma unroll
    for (int mt = 0; mt < 2; ++mt) {
        #pragma unroll
        for (int reg = 0; reg < 4; ++reg) {
            const int row = m0 + wave * 32 + mt * 16 + orow + reg;
            if (row >= batch) continue;
            float* op = out + (size_t)row * OUTW + g * OPG;
            #pragma unroll
            for (int nt = 0; nt < 4; ++nt) {
                const int o = nt * 16 + ocol;
                if (o < OPG) op[o] = fmaxf(acc[mt][nt][reg], 0.f);
            }
        }
    }
}

extern "C" void kernel_launch(void* const* d_in, const int* in_sizes, int n_in,
                              void* d_out, int out_size, void* d_ws, size_t ws_size,
                              hipStream_t stream) {
    const float* x = (const float*)d_in[0];   // (batch, 10000) fp32
    const float* W = (const float*)d_in[1];   // (39, 50, 500) fp32
    float* out     = (float*)d_out;           // (batch, 1950) fp32

    const int batch = in_sizes[0] / INPUT;    // 4096
    dim3 grid(GROUPS, (batch + BM - 1) / BM); // 39 x 32 = 1248 blocks
    peak_binner_kernel<<<grid, dim3(256), 0, stream>>>(x, W, out, batch);
}

// Round 2
// 302.315 us; speedup vs baseline: 1.0846x; 1.0846x over previous
//
#include <hip/hip_runtime.h>
#include <hip/hip_bf16.h>

// PeakBinner: out[b, g*50+o] = relu( sum_k x[b, g*250+k] * W[g,o,k] )
// Round 2: barrier-free main loop. B (W[g]) staged in LDS per 256-wide K-half;
// A fragments loaded DIRECTLY from global (8 consecutive k per lane), bf16
// conversion in registers. Latency hidden by ILP + 4 blocks/CU, no vmcnt(0)
// barrier drains in the K-loop.

constexpr int INPUT  = 10000;
constexpr int GROUPS = 39;
constexpr int GS     = 500;
constexpr int STEP   = 250;
constexpr int OPG    = 50;
constexpr int OUTW   = GROUPS * OPG;   // 1950

constexpr int BM  = 128;               // rows per block (4 waves x 32)
constexpr int KH  = 256;               // K per LDS B-half (2 halves cover 512)
constexpr int LDB = KH + 8;            // shorts; 528 B row stride: 16B-aligned,
                                       // o-stride = 4 banks -> 2-way (free)

typedef __attribute__((ext_vector_type(8))) short  short8;   // bf16x8 frag
typedef __attribute__((ext_vector_type(4))) float  float4v;  // fp32x4 acc

__device__ __forceinline__ unsigned bf2pack(float a, float b) {
    // RNE fp32->bf16, packed pair (inputs finite)
    union { float f; unsigned u; } x, y; x.f = a; y.f = b;
    unsigned lo = (x.u + 0x7fffu + ((x.u >> 16) & 1u)) >> 16;
    unsigned hi = (y.u + 0x7fffu + ((y.u >> 16) & 1u)) & 0xffff0000u;
    return hi | lo;
}

template<bool TAIL>
__device__ __forceinline__ short8 load_a_frag(const float* base, int koff, int kglob) {
    // base already includes row*INPUT + col0 + fk; loads 8 consecutive fp32.
    // TAIL: zero chunks whose window-k >= GS (chunks 2-aligned, GS even).
    float2 c0 = {0.f, 0.f}, c1 = {0.f, 0.f}, c2 = {0.f, 0.f}, c3 = {0.f, 0.f};
    if (!TAIL) {
        c0 = *(const float2*)(base + koff);
        c1 = *(const float2*)(base + koff + 2);
        c2 = *(const float2*)(base + koff + 4);
        c3 = *(const float2*)(base + koff + 6);
    } else {
        if (kglob + 2 <= GS) c0 = *(const float2*)(base + koff);
        if (kglob + 4 <= GS) c1 = *(const float2*)(base + koff + 2);
        if (kglob + 6 <= GS) c2 = *(const float2*)(base + koff + 4);
        if (kglob + 8 <= GS) c3 = *(const float2*)(base + koff + 6);
    }
    union { short8 s; unsigned u[4]; } f;
    f.u[0] = bf2pack(c0.x, c0.y);
    f.u[1] = bf2pack(c1.x, c1.y);
    f.u[2] = bf2pack(c2.x, c2.y);
    f.u[3] = bf2pack(c3.x, c3.y);
    return f.s;
}

__global__ __launch_bounds__(256, 4)
void peak_binner_kernel(const float* __restrict__ x,
                        const float* __restrict__ W,
                        float* __restrict__ out, int batch)
{
    __shared__ __align__(16) short Bs[64 * LDB];  // rows 50..63 never written:
                                                  // only feed masked outputs

    const int g    = blockIdx.x;        // group 0..38
    const int m0   = blockIdx.y * BM;   // batch-row tile base
    const int tid  = threadIdx.x;
    const int lane = tid & 63;
    const int wave = tid >> 6;

    const int fm = lane & 15;           // fragment row (m for A, o for B)
    const int fk = (lane >> 4) * 8;     // fragment k base

    const long  col0 = (long)g * STEP;
    const float* Wg  = W + (size_t)g * OPG * GS;

    // Per-mt A base pointers (batch is a multiple of BM -> rows always valid)
    const float* Abase[2];
    #pragma unroll
    for (int mt = 0; mt < 2; ++mt) {
        const int row = m0 + wave * 32 + mt * 16 + fm;
        Abase[mt] = x + (size_t)row * INPUT + col0 + fk;
    }

    float4v acc[2][4];
    #pragma unroll
    for (int i = 0; i < 2; ++i)
        #pragma unroll
        for (int j = 0; j < 4; ++j)
            acc[i][j] = {0.f, 0.f, 0.f, 0.f};

    #pragma unroll
    for (int h = 0; h < 2; ++h) {
        const int k0 = h * KH;
        if (h) __syncthreads();          // waves done reading previous half

        // ---- stage B half: 50 x 256 fp32 -> bf16, zero-pad k >= 500 ----
        for (int c = tid; c < OPG * (KH / 2); c += 256) {   // 25 iters exactly
            const int o  = c >> 7;                // c / 128
            const int kc = (c & 127) << 1;        // local k, even
            const int k  = k0 + kc;
            float2 v = {0.f, 0.f};
            if (k < GS) v = *(const float2*)(Wg + o * GS + k);
            *(unsigned*)&Bs[o * LDB + kc] = bf2pack(v.x, v.y);
        }
        __syncthreads();

        // ---- barrier-free K loop over this half ----
        #pragma unroll
        for (int kk = 0; kk < KH; kk += 32) {
            short8 a[2];
            if (h == 1 && kk == KH - 32) {
                a[0] = load_a_frag<true>(Abase[0], k0 + kk, k0 + kk + fk);
                a[1] = load_a_frag<true>(Abase[1], k0 + kk, k0 + kk + fk);
            } else {
                a[0] = load_a_frag<false>(Abase[0], k0 + kk, 0);
                a[1] = load_a_frag<false>(Abase[1], k0 + kk, 0);
            }
            short8 b[4];
            #pragma unroll
            for (int nt = 0; nt < 4; ++nt)
                b[nt] = *(const short8*)&Bs[(nt * 16 + fm) * LDB + kk + fk];
            #pragma unroll
            for (int mt = 0; mt < 2; ++mt)
                #pragma unroll
                for (int nt = 0; nt < 4; ++nt)
                    acc[mt][nt] = __builtin_amdgcn_mfma_f32_16x16x32_bf16(
                        a[mt], b[nt], acc[mt][nt], 0, 0, 0);
        }
    }

    // ---- epilogue: C/D layout col=lane&15, row=(lane>>4)*4+reg; relu ----
    const int orow = (lane >> 4) * 4;
    const int ocol = lane & 15;
    #pragma unroll
    for (int mt = 0; mt < 2; ++mt) {
        #pragma unroll
        for (int reg = 0; reg < 4; ++reg) {
            const int row = m0 + wave * 32 + mt * 16 + orow + reg;
            if (row >= batch) continue;
            float* op = out + (size_t)row * OUTW + g * OPG;
            #pragma unroll
            for (int nt = 0; nt < 4; ++nt) {
                const int o = nt * 16 + ocol;
                if (o < OPG) op[o] = fmaxf(acc[mt][nt][reg], 0.f);
            }
        }
    }
}

extern "C" void kernel_launch(void* const* d_in, const int* in_sizes, int n_in,
                              void* d_out, int out_size, void* d_ws, size_t ws_size,
                              hipStream_t stream) {
    const float* x = (const float*)d_in[0];   // (batch, 10000) fp32
    const float* W = (const float*)d_in[1];   // (39, 50, 500) fp32
    float* out     = (float*)d_out;           // (batch, 1950) fp32

    const int batch = in_sizes[0] / INPUT;    // 4096
    dim3 grid(GROUPS, (batch + BM - 1) / BM); // 39 x 32 = 1248 blocks
    peak_binner_kernel<<<grid, dim3(256), 0, stream>>>(x, W, out, batch);
}

// Round 3
// 297.852 us; speedup vs baseline: 1.1008x; 1.0150x over previous
//
#include <hip/hip_runtime.h>
#include <hip/hip_bf16.h>

// PeakBinner: out[b, g*50+o] = relu( sum_k x[b, g*250+k] * W[g,o,k] )
// Round 3: async global->LDS staging (global_load_lds) for BOTH operands as
// raw fp32; bf16 conversion at fragment-read time. MLP comes from issuing a
// whole 52KB stage asynchronously before one drain (m97 pattern), not from
// per-thread VGPR loads (rounds 1-2: ~0.5 loads in flight -> 1.9 TB/s).

constexpr int INPUT  = 10000;
constexpr int GROUPS = 39;
constexpr int GS     = 500;
constexpr int STEP   = 250;
constexpr int OPG    = 50;
constexpr int OUTW   = GROUPS * OPG;   // 1950

constexpr int BM  = 128;
constexpr int BK  = 64;
constexpr int NST = 8;                 // 8*64 = 512 >= 500
constexpr int RCH  = 17;               // 16B chunks per LDS row (272B stride:
                                       // 68 dwords = 4 banks mod 32 -> 2-way, free)
constexpr int ROWB = RCH * 16;         // 272 bytes
constexpr int A_BYTES = BM * ROWB;     // 34816
constexpr int B_BYTES = 64 * ROWB;     // 17408 (rows >=50 are dup/garbage, masked)

typedef __attribute__((ext_vector_type(8))) short  short8;
typedef __attribute__((ext_vector_type(4))) float  float4v;

typedef const __attribute__((address_space(1))) unsigned int* gptr_t;
typedef __attribute__((address_space(3))) unsigned int*       lptr_t;

__device__ __forceinline__ void gl_lds16(const void* g, void* l) {
    // LDS dst is wave-uniform base; HW scatters lane*16 (m104/m108).
    __builtin_amdgcn_global_load_lds((gptr_t)(unsigned long long)g,
                                     (lptr_t)(unsigned int)(unsigned long long)l,
                                     16, 0, 0);
}
__device__ __forceinline__ void gl_lds4(const void* g, void* l) {
    __builtin_amdgcn_global_load_lds((gptr_t)(unsigned long long)g,
                                     (lptr_t)(unsigned int)(unsigned long long)l,
                                     4, 0, 0);
}

__device__ __forceinline__ unsigned bf2pack(float a, float b) {
    union { float f; unsigned u; } x, y; x.f = a; y.f = b;
    unsigned lo = (x.u + 0x7fffu + ((x.u >> 16) & 1u)) >> 16;
    unsigned hi = (y.u + 0x7fffu + ((y.u >> 16) & 1u)) & 0xffff0000u;
    return hi | lo;
}
__device__ __forceinline__ short8 pack8(float4 lo, float4 hi) {
    union { short8 s; unsigned u[4]; } r;
    r.u[0] = bf2pack(lo.x, lo.y);
    r.u[1] = bf2pack(lo.z, lo.w);
    r.u[2] = bf2pack(hi.x, hi.y);
    r.u[3] = bf2pack(hi.z, hi.w);
    return r.s;
}

__global__ __launch_bounds__(256, 3)
void peak_binner_kernel(const float* __restrict__ x,
                        const float* __restrict__ W,
                        float* __restrict__ out, int batch)
{
    __shared__ __align__(16) char lds[A_BYTES + B_BYTES];   // 51 KB -> 3 blocks/CU
    char* Abuf = lds;
    char* Bbuf = lds + A_BYTES;

    const int g    = blockIdx.x;
    const int m0   = blockIdx.y * BM;
    const int tid  = threadIdx.x;
    const int lane = tid & 63;
    const int wave = tid >> 6;
    const int fm   = lane & 15;
    const int l4   = lane >> 4;

    const float* xg = x + (size_t)g * STEP;
    const float* Wg = W + (size_t)g * OPG * GS;
    const bool aligned16 = ((g & 1) == 0);   // col0 bytes % 16 == 0 iff g even

    float4v acc[2][4];
    #pragma unroll
    for (int i = 0; i < 2; ++i)
        #pragma unroll
        for (int j = 0; j < 4; ++j)
            acc[i][j] = {0.f, 0.f, 0.f, 0.f};

    for (int stage = 0; stage < NST; ++stage) {
        const int kb = stage * BK;
        __syncthreads();                       // prev compute done reading LDS

        // ---- A staging: 128 rows x 68 dwords (k chunk 16 = harmless dup) ----
        if (aligned16) {
            const int cmax = (GS - 1 - kb) >> 2;       // 12 on last stage
            for (int j = wave; j < (A_BYTES / 1024); j += 4) {   // 34 calls
                const int f   = j * 64 + lane;         // flat 16B-chunk index
                const int row = f / RCH;
                int c = f - row * RCH;                 // 0..16
                c = min(c, cmax);
                const int grow = min(m0 + row, batch - 1);
                gl_lds16(xg + (size_t)grow * INPUT + kb + 4 * c, Abuf + j * 1024);
            }
        } else {
            const int qmax = GS - 1 - kb;              // 51 on last stage
            for (int j = wave; j < (A_BYTES / 256); j += 4) {    // 136 calls
                const int d   = j * 64 + lane;         // flat dword index
                const int row = d / (RCH * 4);
                int q = d - row * (RCH * 4);           // 0..67
                q = min(q, qmax);
                const int grow = min(m0 + row, batch - 1);
                gl_lds4(xg + (size_t)grow * INPUT + kb + q, Abuf + j * 256);
            }
        }
        // ---- B staging (W is always 16B-aligned) ----
        {
            const int cmax = (GS - 4 - kb) >> 2;       // 12 on last stage
            for (int j = wave; j < (B_BYTES / 1024); j += 4) {   // 17 calls
                const int f   = j * 64 + lane;
                const int row = f / RCH;               // 0..63
                int c = f - row * RCH;
                c = min(c, cmax);
                const int ro = min(row, OPG - 1);      // rows >=50: dup row 49
                gl_lds16(Wg + ro * GS + kb + 4 * c, Bbuf + j * 1024);
            }
        }
        __syncthreads();                       // drains vmcnt(0): DMA complete

        if (stage == NST - 1) {
            // zero B chunks holding k >= 500 (k-local 52..63); A junk there
            // then multiplies zero. Chunk 16 never read by fragments.
            if (tid < 192) {
                const int row = tid / 3;
                const int c   = 13 + (tid - row * 3);
                *(float4*)(Bbuf + row * ROWB + c * 16) = float4{0.f, 0.f, 0.f, 0.f};
            }
            __syncthreads();
        }

        // ---- compute: 2 MFMA k-steps; fp32 LDS -> bf16 frags in regs ----
        #pragma unroll
        for (int kk = 0; kk < 2; ++kk) {
            const int pb = (kk * 8 + l4 * 2) * 16;     // chunk byte offset
            short8 a[2], b[4];
            #pragma unroll
            for (int mt = 0; mt < 2; ++mt) {
                const char* base = Abuf + (wave * 32 + mt * 16 + fm) * ROWB + pb;
                float4 lo = *(const float4*)(base);
                float4 hi = *(const float4*)(base + 16);
                a[mt] = pack8(lo, hi);
            }
            #pragma unroll
            for (int nt = 0; nt < 4; ++nt) {
                const char* base = Bbuf + (nt * 16 + fm) * ROWB + pb;
                float4 lo = *(const float4*)(base);
                float4 hi = *(const float4*)(base + 16);
                b[nt] = pack8(lo, hi);
            }
            #pragma unroll
            for (int mt = 0; mt < 2; ++mt)
                #pragma unroll
                for (int nt = 0; nt < 4; ++nt)
                    acc[mt][nt] = __builtin_amdgcn_mfma_f32_16x16x32_bf16(
                        a[mt], b[nt], acc[mt][nt], 0, 0, 0);
        }
    }

    // ---- epilogue: C/D layout col=lane&15, row=(lane>>4)*4+reg; relu ----
    const int orow = (lane >> 4) * 4;
    const int ocol = lane & 15;
    #pragma unroll
    for (int mt = 0; mt < 2; ++mt) {
        #pragma unroll
        for (int reg = 0; reg < 4; ++reg) {
            const int row = m0 + wave * 32 + mt * 16 + orow + reg;
            if (row >= batch) continue;
            float* op = out + (size_t)row * OUTW + g * OPG;
            #pragma unroll
            for (int nt = 0; nt < 4; ++nt) {
                const int o = nt * 16 + ocol;
                if (o < OPG) op[o] = fmaxf(acc[mt][nt][reg], 0.f);
            }
        }
    }
}

extern "C" void kernel_launch(void* const* d_in, const int* in_sizes, int n_in,
                              void* d_out, int out_size, void* d_ws, size_t ws_size,
                              hipStream_t stream) {
    const float* x = (const float*)d_in[0];   // (batch, 10000) fp32
    const float* W = (const float*)d_in[1];   // (39, 50, 500) fp32
    float* out     = (float*)d_out;           // (batch, 1950) fp32

    const int batch = in_sizes[0] / INPUT;    // 4096
    dim3 grid(GROUPS, (batch + BM - 1) / BM); // 39 x 32 = 1248 blocks
    peak_binner_kernel<<<grid, dim3(256), 0, stream>>>(x, W, out, batch);
}